// Round 3
// baseline (190.677 us; speedup 1.0000x reference)
//
#include <hip/hip_runtime.h>
#include <stdint.h>

#define BQ 4
#define CC 3
#define MM 4096
#define NN 8192
#define KK 16
#define NP_OFF (BQ*CC*MM*KK)   // 786432 floats of coords, then indices
#define BLOCK 512
#define WAVES 8
#define CHUNK 2048             // points per LDS chunk (32 KB of float4)
#define NCHUNK (NN/CHUNK)      // 4
#define CSTEPS (CHUNK/64)      // 32 steps per chunk per lane
#define STEPS (NN/64)          // 128 distances per lane

__global__ __launch_bounds__(BLOCK, 2) void knn_kernel(
    const float* __restrict__ query,
    const float* __restrict__ points,
    float* __restrict__ out)
{
    __shared__ float4 pts[CHUNK];             // 32 KB
    __shared__ unsigned int cbuf[WAVES][128]; // 64 x (distbits, idx) per wave

    const int tid  = threadIdx.x;
    const int lane = tid & 63;
    const int wv   = tid >> 6;
    const int bid  = blockIdx.x;          // 0..2047
    const int b    = bid >> 9;            // 512 blocks per batch
    const int m    = ((bid & 511) << 3) | wv;  // one row per wave

    const float* pb = points + b * (CC * NN);
    const float* qb = query  + b * (CC * MM);

    // |q|^2 numpy-style: squares rounded individually, sequential add, NO fma
    const float qx = qb[m];
    const float qy = qb[MM + m];
    const float qz = qb[2*MM + m];
    const float q2 = __fadd_rn(__fadd_rn(__fmul_rn(qx,qx), __fmul_rn(qy,qy)),
                               __fmul_rn(qz,qz));

    float darr[STEPS];
    float b0 = __builtin_inff(), b1 = __builtin_inff();  // per-lane top-2 (sorted)

    // ---- Pass 1: f32 distances, numpy-rounding-exact ----
    #pragma unroll
    for (int ch = 0; ch < NCHUNK; ++ch) {
        __syncthreads();   // previous chunk fully consumed
        for (int i = tid; i < CHUNK; i += BLOCK) {
            int n = ch * CHUNK + i;
            float px = pb[n];
            float py = pb[NN + n];
            float pz = pb[2*NN + n];
            // |p|^2 numpy-style (separate ufuncs: mul then sequential add)
            float p2 = __fadd_rn(__fadd_rn(__fmul_rn(px,px), __fmul_rn(py,py)),
                                 __fmul_rn(pz,pz));
            pts[i] = make_float4(px, py, pz, p2);
        }
        __syncthreads();
        #pragma unroll
        for (int t = 0; t < CSTEPS; ++t) {
            float4 P = pts[t * 64 + lane];
            // einsum dot: gcc -ffp-contract=fast FMA chain, ascending c:
            //   acc = fma(q2*p2, fma(q1*p1, q0*p0))
            float dot = __builtin_fmaf(qz, P.z,
                         __builtin_fmaf(qy, P.y, __fmul_rn(qx, P.x)));
            // (q2 + p2) - 2*dot : per-ufunc rounding (2*dot exact)
            float d = __fsub_rn(__fadd_rn(q2, P.w), __fmul_rn(2.0f, dot));
            darr[ch * CSTEPS + t] = d;
            float nb1 = fminf(fmaxf(d, b0), b1);   // sorted top-2 update
            b0 = fminf(b0, d);
            b1 = nb1;
        }
    }

    // ---- tau: 16th smallest of union of per-lane top-2 (>= true 16th) ----
    float h = b0, h2 = b1;
    float tau = 0.0f;
    #pragma unroll 1
    for (int r = 0; r < KK; ++r) {
        float mn = h;
        #pragma unroll
        for (int off = 32; off > 0; off >>= 1)
            mn = fminf(mn, __shfl_xor(mn, off, 64));
        unsigned long long wm = __ballot(h == mn);
        int winner = __ffsll((long long)wm) - 1;
        if (lane == winner) { h = h2; h2 = __builtin_inff(); }
        tau = mn;
    }

    // ---- Pass 2: ballot-compact (dist,idx) candidates with d <= tau ----
    // inclusive <= so all tau-ties become candidates; stable sort resolves.
    unsigned int* buf = cbuf[wv];
    const unsigned long long lmask_lt = (1ull << lane) - 1ull;
    int base = 0;
    #pragma unroll
    for (int t = 0; t < STEPS; ++t) {
        bool p = (darr[t] <= tau);
        unsigned long long mk = __ballot(p);
        if (mk) {
            int pos = base + (int)__popcll(mk & lmask_lt);
            if (p && pos < 64) {
                buf[2*pos]     = __float_as_uint(darr[t]);
                buf[2*pos + 1] = (unsigned)(t * 64 + lane);
            }
            base += (int)__popcll(mk);
        }
    }
    int cnt = base < 64 ? base : 64;   // guaranteed >= 16
    __syncthreads();                   // LDS write->read ordering

    // ---- 64-lane bitonic sort on (f32 key, idx) lexicographic ascending ----
    unsigned int kb = 0xffffffffu, idx = 0xffffffffu;
    if (lane < cnt) {
        unsigned int fb = buf[2*lane];
        kb  = (fb & 0x80000000u) ? ~fb : (fb | 0x80000000u); // order-preserving
        idx = buf[2*lane + 1];
    }
    #pragma unroll
    for (int k = 2; k <= 64; k <<= 1) {
        #pragma unroll
        for (int j = k >> 1; j > 0; j >>= 1) {
            unsigned int ok = __shfl_xor(kb, j, 64);
            unsigned int oi = __shfl_xor(idx, j, 64);
            bool up = ((lane & k) == 0);
            bool takeMin = (((lane & j) == 0) == up);
            bool selfLess = (kb < ok) || (kb == ok && idx < oi);
            if (selfLess != takeMin) { kb = ok; idx = oi; }
        }
    }

    // ---- output: lanes 0..15 hold ascending (dist, idx) winners ----
    if (lane < KK) {
        int oi = (int)idx;
        out[NP_OFF + (b * MM + m) * KK + lane] = (float)oi;
        float px = pb[oi];
        float py = pb[NN + oi];
        float pz = pb[2*NN + oi];
        out[((b * CC + 0) * MM + m) * KK + lane] = px;
        out[((b * CC + 1) * MM + m) * KK + lane] = py;
        out[((b * CC + 2) * MM + m) * KK + lane] = pz;
    }
}

extern "C" void kernel_launch(void* const* d_in, const int* in_sizes, int n_in,
                              void* d_out, int out_size, void* d_ws, size_t ws_size,
                              hipStream_t stream) {
    // d_in[0] = k (scalar, =16), d_in[1] = query f32 [4,3,4096],
    // d_in[2] = points f32 [4,3,8192]
    const float* query  = (const float*)d_in[1];
    const float* points = (const float*)d_in[2];
    float* out = (float*)d_out;
    dim3 grid(BQ * (MM / WAVES));   // 2048 blocks, 1 row per wave
    dim3 block(BLOCK);
    knn_kernel<<<grid, block, 0, stream>>>(query, points, out);
}

// Round 4
// 143.549 us; speedup vs baseline: 1.3283x; 1.3283x over previous
//
#include <hip/hip_runtime.h>
#include <stdint.h>

#define BQ 4
#define CC 3
#define MM 4096
#define NN 8192
#define KK 16
#define NP_OFF (BQ*CC*MM*KK)    // coords first, then indices
#define BLOCK 256
#define WAVES 4
#define RPW 8                    // rows per wave
#define ROWS (WAVES*RPW)         // 32 rows per block
#define CHUNK 2048               // points per LDS chunk (32 KB of float4)
#define NCHUNK (NN/CHUNK)        // 4
#define CSTEPS (CHUNK/64)        // 32 wave-steps per chunk
#define EPS 1e-3f                // slack: folded-chain d' vs reference d (~1e-5 max)

__device__ __forceinline__ float rfl(float x) {
    return __uint_as_float((unsigned)__builtin_amdgcn_readfirstlane((int)__float_as_uint(x)));
}

__global__ __launch_bounds__(BLOCK, 4) void knn_kernel(
    const float* __restrict__ query,
    const float* __restrict__ points,
    float* __restrict__ out)
{
    __shared__ float4 pts[CHUNK];          // 32 KB: {x,y,z, -0.5*p2}
    __shared__ unsigned cand[ROWS][64];    // 8 KB candidate indices
    __shared__ unsigned scnt[ROWS];

    const int tid  = threadIdx.x;
    const int lane = tid & 63;
    const int wv   = tid >> 6;
    const int bid  = blockIdx.x;           // 0..511
    const int b    = bid >> 7;             // 128 blocks per batch
    const int rb   = (bid & 127) * ROWS;   // first row of this block

    const float* pb = points + b * (CC * NN);
    const float* qb = query  + b * (CC * MM);

    if (tid < ROWS) scnt[tid] = 0;

    // per-row query scalars (wave-uniform -> SGPRs) + exact reference q2
    float qx[RPW], qy[RPW], qz[RPW], q2[RPW], b0[RPW];
    #pragma unroll
    for (int r = 0; r < RPW; ++r) {
        int m = rb + wv * RPW + r;
        float x = rfl(qb[m]);
        float y = rfl(qb[MM + m]);
        float z = rfl(qb[2*MM + m]);
        qx[r] = x; qy[r] = y; qz[r] = z;
        q2[r] = rfl(__fadd_rn(__fadd_rn(__fmul_rn(x,x), __fmul_rn(y,y)),
                              __fmul_rn(z,z)));
        b0[r] = __builtin_inff();
    }

    // ---- Pass 1: per-lane per-row min distance (approx folded chain) ----
    #pragma unroll 1
    for (int ch = 0; ch < NCHUNK; ++ch) {
        __syncthreads();
        for (int i = tid; i < CHUNK; i += BLOCK) {
            int n = ch * CHUNK + i;
            float px = pb[n], py = pb[NN + n], pz = pb[2*NN + n];
            float p2 = __fadd_rn(__fadd_rn(__fmul_rn(px,px), __fmul_rn(py,py)),
                                 __fmul_rn(pz,pz));
            pts[i] = make_float4(px, py, pz, -0.5f * p2);
        }
        __syncthreads();
        #pragma unroll 4
        for (int t = 0; t < CSTEPS; ++t) {
            float4 P = pts[(t << 6) + lane];
            #pragma unroll
            for (int r = 0; r < RPW; ++r) {
                float dotf = __builtin_fmaf(qz[r], P.z,
                              __builtin_fmaf(qy[r], P.y,
                               __builtin_fmaf(qx[r], P.x, P.w)));
                float dp = __builtin_fmaf(-2.0f, dotf, q2[r]); // ~ q2+p2-2dot
                b0[r] = fminf(b0[r], dp);
            }
        }
    }

    // ---- tau_r = 16th smallest of 64 lane-minima (upper bound of true 16th)
    //      -> row-constant threshold for the folded-dot test ----
    float rc[RPW];
    #pragma unroll
    for (int r = 0; r < RPW; ++r) {
        float v = b0[r];
        #pragma unroll
        for (int k = 2; k <= 64; k <<= 1) {
            #pragma unroll
            for (int j = k >> 1; j > 0; j >>= 1) {
                float o = __shfl_xor(v, j, 64);
                bool keepmin = (((lane & j) == 0) == ((lane & k) == 0));
                v = keepmin ? fminf(v, o) : fmaxf(v, o);
            }
        }
        float tau = __shfl(v, 15, 64);
        // d' <= tau+EPS  <=>  dotf >= 0.5*(q2 - tau - EPS)
        rc[r] = rfl(0.5f * (q2[r] - tau - EPS));
    }

    // ---- Pass 2: recompute folded dot, collect candidate indices ----
    #pragma unroll 1
    for (int ch = 0; ch < NCHUNK; ++ch) {
        __syncthreads();   // also covers scnt zero-init visibility (first iter)
        for (int i = tid; i < CHUNK; i += BLOCK) {
            int n = ch * CHUNK + i;
            float px = pb[n], py = pb[NN + n], pz = pb[2*NN + n];
            float p2 = __fadd_rn(__fadd_rn(__fmul_rn(px,px), __fmul_rn(py,py)),
                                 __fmul_rn(pz,pz));
            pts[i] = make_float4(px, py, pz, -0.5f * p2);
        }
        __syncthreads();
        #pragma unroll 4
        for (int t = 0; t < CSTEPS; ++t) {
            float4 P = pts[(t << 6) + lane];
            int n = ch * CHUNK + (t << 6) + lane;
            #pragma unroll
            for (int r = 0; r < RPW; ++r) {
                float dotf = __builtin_fmaf(qz[r], P.z,
                              __builtin_fmaf(qy[r], P.y,
                               __builtin_fmaf(qx[r], P.x, P.w)));
                if (dotf >= rc[r]) {                     // rare (~18/row total)
                    unsigned pos = atomicAdd(&scnt[wv*RPW + r], 1u);
                    if (pos < 64u) cand[wv*RPW + r][pos] = (unsigned)n;
                }
            }
        }
    }
    __syncthreads();

    // ---- Epilogue: exact reference distance for candidates, bitonic top-16 ----
    #pragma unroll
    for (int r = 0; r < RPW; ++r) {
        int row = wv * RPW + r;
        unsigned c = scnt[row]; if (c > 64u) c = 64u;   // >=16 guaranteed
        unsigned kb = 0xffffffffu, id = 0xffffffffu;
        if (lane < (int)c) {
            id = cand[row][lane];
            float px = pb[id], py = pb[NN + id], pz = pb[2*NN + id];
            // bit-exact reference rounding (validated in R3):
            float p2 = __fadd_rn(__fadd_rn(__fmul_rn(px,px), __fmul_rn(py,py)),
                                 __fmul_rn(pz,pz));
            float dot = __builtin_fmaf(qz[r], pz,
                         __builtin_fmaf(qy[r], py, __fmul_rn(qx[r], px)));
            float d = __fsub_rn(__fadd_rn(q2[r], p2), __fmul_rn(2.0f, dot));
            unsigned fb = __float_as_uint(d);
            kb = (fb & 0x80000000u) ? ~fb : (fb | 0x80000000u);
        }
        #pragma unroll
        for (int k = 2; k <= 64; k <<= 1) {
            #pragma unroll
            for (int j = k >> 1; j > 0; j >>= 1) {
                unsigned ok = __shfl_xor(kb, j, 64);
                unsigned oi = __shfl_xor(id, j, 64);
                bool takeMin  = (((lane & j) == 0) == ((lane & k) == 0));
                bool selfLess = (kb < ok) || (kb == ok && id < oi);
                if (selfLess != takeMin) { kb = ok; id = oi; }
            }
        }
        if (lane < KK) {
            int m  = rb + row;
            int oi = (int)id;
            out[NP_OFF + (b * MM + m) * KK + lane] = (float)oi;
            out[((b * CC + 0) * MM + m) * KK + lane] = pb[oi];
            out[((b * CC + 1) * MM + m) * KK + lane] = pb[NN + oi];
            out[((b * CC + 2) * MM + m) * KK + lane] = pb[2*NN + oi];
        }
    }
}

extern "C" void kernel_launch(void* const* d_in, const int* in_sizes, int n_in,
                              void* d_out, int out_size, void* d_ws, size_t ws_size,
                              hipStream_t stream) {
    // d_in[0] = k (scalar, =16), d_in[1] = query f32 [4,3,4096],
    // d_in[2] = points f32 [4,3,8192]
    const float* query  = (const float*)d_in[1];
    const float* points = (const float*)d_in[2];
    float* out = (float*)d_out;
    dim3 grid(BQ * (MM / ROWS));    // 512 blocks, 32 rows each (8 per wave)
    dim3 block(BLOCK);
    knn_kernel<<<grid, block, 0, stream>>>(query, points, out);
}

// Round 5
// 113.769 us; speedup vs baseline: 1.6760x; 1.2618x over previous
//
#include <hip/hip_runtime.h>
#include <stdint.h>

#define BQ 4
#define CC 3
#define MM 4096
#define NN 8192
#define KK 16
#define NP_OFF (BQ*CC*MM*KK)    // coords first, then indices
#define BLOCK 256
#define WAVES 4
#define RPW 4                    // rows per wave
#define ROWS (WAVES*RPW)         // 16 rows per block
#define CHUNK 1024               // points per LDS buffer (16 KB of float4)
#define NCH (NN/CHUNK)           // 8
#define CST (CHUNK/64)           // 16 wave-steps per chunk
#define EPSD 1e-4f               // dotf-space slack (folded vs reference ~1e-6)

__device__ __forceinline__ float rfl(float x) {
    return __uint_as_float((unsigned)__builtin_amdgcn_readfirstlane((int)__float_as_uint(x)));
}

__global__ __launch_bounds__(BLOCK, 4) void knn_kernel(
    const float* __restrict__ query,
    const float* __restrict__ points,
    float* __restrict__ out)
{
    __shared__ float4 pts[2][CHUNK];       // 32 KB, double-buffered {x,y,z,-p2/2}
    __shared__ unsigned cand[ROWS][64];    // 4 KB candidate indices
    __shared__ unsigned scnt[ROWS];

    const int tid  = threadIdx.x;
    const int lane = tid & 63;
    const int wv   = tid >> 6;
    const int bid  = blockIdx.x;           // 0..1023
    const int b    = bid >> 8;             // 256 blocks per batch
    const int rb   = (bid & 255) * ROWS;   // first row of this block

    const float* pb = points + b * (CC * NN);
    const float* qb = query  + b * (CC * MM);

    if (tid < ROWS) scnt[tid] = 0;

    // per-row query scalars (wave-uniform -> SGPRs) + exact reference q2
    float qx[RPW], qy[RPW], qz[RPW], q2[RPW], dm[RPW];
    #pragma unroll
    for (int r = 0; r < RPW; ++r) {
        int m = rb + wv * RPW + r;
        float x = rfl(qb[m]);
        float y = rfl(qb[MM + m]);
        float z = rfl(qb[2*MM + m]);
        qx[r] = x; qy[r] = y; qz[r] = z;
        q2[r] = rfl(__fadd_rn(__fadd_rn(__fmul_rn(x,x), __fmul_rn(y,y)),
                              __fmul_rn(z,z)));
        dm[r] = -__builtin_inff();         // per-lane MAX of folded dot
    }

    // ---- staging helper: pack {x,y,z,-0.5*p2} (identical rounding both passes)
    auto stage = [&](int ch, int bi) {
        #pragma unroll
        for (int i = 0; i < CHUNK / BLOCK; ++i) {       // 4 iters
            int ii = i * BLOCK + tid;
            int n  = ch * CHUNK + ii;
            float px = pb[n], py = pb[NN + n], pz = pb[2*NN + n];
            float p2 = __fadd_rn(__fadd_rn(__fmul_rn(px,px), __fmul_rn(py,py)),
                                 __fmul_rn(pz,pz));
            pts[bi][ii] = make_float4(px, py, pz, -0.5f * p2);
        }
    };

    // ---- Pass 1: per-lane per-row max folded dot (3 fma + 1 max per pt/row)
    auto comp1 = [&](int bi) {
        #pragma unroll
        for (int t = 0; t < CST; ++t) {
            float4 P = pts[bi][(t << 6) + lane];
            #pragma unroll
            for (int r = 0; r < RPW; ++r) {
                float dotf = __builtin_fmaf(qz[r], P.z,
                              __builtin_fmaf(qy[r], P.y,
                               __builtin_fmaf(qx[r], P.x, P.w)));
                dm[r] = fmaxf(dm[r], dotf);
            }
        }
    };

    stage(0, 0);
    #pragma unroll 1
    for (int ch = 0; ch < NCH; ch += 2) {
        __syncthreads();                       // buf0(ch) ready
        if (ch + 1 < NCH) stage(ch + 1, 1);    // overlap with compute
        comp1(0);
        __syncthreads();                       // buf1 ready; buf0 reads done
        if (ch + 2 < NCH) stage(ch + 2, 0);
        if (ch + 1 < NCH) comp1(1);
    }

    // ---- tau_dot[r] = 16th LARGEST of 64 lane-maxes (<= true 16th largest
    //      dotf; mirrored proof of R4's threshold) -> row-constant SGPR
    float rc[RPW];
    #pragma unroll
    for (int r = 0; r < RPW; ++r) {
        float v = dm[r];
        #pragma unroll
        for (int k = 2; k <= 64; k <<= 1) {
            #pragma unroll
            for (int j = k >> 1; j > 0; j >>= 1) {
                float o = __shfl_xor(v, j, 64);
                bool keepmin = (((lane & j) == 0) == ((lane & k) == 0));
                v = keepmin ? fminf(v, o) : fmaxf(v, o);
            }
        }
        float tau = __shfl(v, 64 - KK, 64);    // ascending: idx 48 = 16th largest
        rc[r] = rfl(tau - EPSD);
    }

    // ---- Pass 2: recompute folded dot, collect candidate indices ----
    auto comp2 = [&](int ch, int bi) {
        #pragma unroll
        for (int t = 0; t < CST; ++t) {
            float4 P = pts[bi][(t << 6) + lane];
            unsigned n = (unsigned)(ch * CHUNK + (t << 6) + lane);
            #pragma unroll
            for (int r = 0; r < RPW; ++r) {
                float dotf = __builtin_fmaf(qz[r], P.z,
                              __builtin_fmaf(qy[r], P.y,
                               __builtin_fmaf(qx[r], P.x, P.w)));
                if (dotf >= rc[r]) {                     // rare (~40/row total)
                    unsigned pos = atomicAdd(&scnt[wv*RPW + r], 1u);
                    if (pos < 64u) cand[wv*RPW + r][pos] = n;
                }
            }
        }
    };

    stage(0, 0);
    #pragma unroll 1
    for (int ch = 0; ch < NCH; ch += 2) {
        __syncthreads();
        if (ch + 1 < NCH) stage(ch + 1, 1);
        comp2(ch, 0);
        __syncthreads();
        if (ch + 2 < NCH) stage(ch + 2, 0);
        if (ch + 1 < NCH) comp2(ch + 1, 1);
    }
    __syncthreads();

    // ---- Epilogue: exact reference distance for candidates, bitonic top-16 ----
    #pragma unroll
    for (int r = 0; r < RPW; ++r) {
        int row = wv * RPW + r;
        unsigned c = scnt[row]; if (c > 64u) c = 64u;   // >=16 guaranteed
        unsigned kb = 0xffffffffu, id = 0xffffffffu;
        if (lane < (int)c) {
            id = cand[row][lane];
            float px = pb[id], py = pb[NN + id], pz = pb[2*NN + id];
            // bit-exact reference rounding (validated R3/R4):
            float p2 = __fadd_rn(__fadd_rn(__fmul_rn(px,px), __fmul_rn(py,py)),
                                 __fmul_rn(pz,pz));
            float dot = __builtin_fmaf(qz[r], pz,
                         __builtin_fmaf(qy[r], py, __fmul_rn(qx[r], px)));
            float d = __fsub_rn(__fadd_rn(q2[r], p2), __fmul_rn(2.0f, dot));
            unsigned fb = __float_as_uint(d);
            kb = (fb & 0x80000000u) ? ~fb : (fb | 0x80000000u);
        }
        #pragma unroll
        for (int k = 2; k <= 64; k <<= 1) {
            #pragma unroll
            for (int j = k >> 1; j > 0; j >>= 1) {
                unsigned ok = __shfl_xor(kb, j, 64);
                unsigned oi = __shfl_xor(id, j, 64);
                bool takeMin  = (((lane & j) == 0) == ((lane & k) == 0));
                bool selfLess = (kb < ok) || (kb == ok && id < oi);
                if (selfLess != takeMin) { kb = ok; id = oi; }
            }
        }
        if (lane < KK) {
            int m  = rb + row;
            int oi = (int)id;
            out[NP_OFF + (b * MM + m) * KK + lane] = (float)oi;
            out[((b * CC + 0) * MM + m) * KK + lane] = pb[oi];
            out[((b * CC + 1) * MM + m) * KK + lane] = pb[NN + oi];
            out[((b * CC + 2) * MM + m) * KK + lane] = pb[2*NN + oi];
        }
    }
}

extern "C" void kernel_launch(void* const* d_in, const int* in_sizes, int n_in,
                              void* d_out, int out_size, void* d_ws, size_t ws_size,
                              hipStream_t stream) {
    // d_in[0] = k (scalar, =16), d_in[1] = query f32 [4,3,4096],
    // d_in[2] = points f32 [4,3,8192]
    const float* query  = (const float*)d_in[1];
    const float* points = (const float*)d_in[2];
    float* out = (float*)d_out;
    dim3 grid(BQ * (MM / ROWS));    // 1024 blocks -> 4 blocks/CU resident
    dim3 block(BLOCK);
    knn_kernel<<<grid, block, 0, stream>>>(query, points, out);
}